// Round 6
// baseline (104.655 us; speedup 1.0000x reference)
//
#include <hip/hip_runtime.h>

#define Bv 2
#define Wv 1024
#define Dv 1024
#define Rv 16

typedef __bf16 bf16;
typedef __attribute__((ext_vector_type(8))) __bf16 bf16x8;
typedef __attribute__((ext_vector_type(4))) __bf16 bf16x4;
typedef __attribute__((ext_vector_type(4))) float f32x4;

static __device__ __forceinline__ float sigmoidf_(float x) {
    return 1.0f / (1.0f + expf(-x));
}

static __device__ __forceinline__ void gload_lds16(const void* g, void* l) {
    __builtin_amdgcn_global_load_lds(
        (const __attribute__((address_space(1))) unsigned int*)g,
        (__attribute__((address_space(3))) unsigned int*)l, 16, 0, 0);
}

// ---------------- RMSNorm: one block per row, 256 threads, D=1024, bf16 out ----------------
template <bool INBF16>
__global__ void rmsnorm_kernel(const void* __restrict__ x,
                               const float* __restrict__ scale,
                               bf16* __restrict__ outb) {
    int row = blockIdx.x;
    int t = threadIdx.x;
    float xv[4];
    if (INBF16) {
        bf16x4 v = *(const bf16x4*)((const bf16*)x + (size_t)row * Dv + t * 4);
        xv[0] = (float)v[0]; xv[1] = (float)v[1]; xv[2] = (float)v[2]; xv[3] = (float)v[3];
    } else {
        float4 v = *(const float4*)((const float*)x + (size_t)row * Dv + t * 4);
        xv[0] = v.x; xv[1] = v.y; xv[2] = v.z; xv[3] = v.w;
    }
    float ss = xv[0] * xv[0] + xv[1] * xv[1] + xv[2] * xv[2] + xv[3] * xv[3];
    for (int off = 32; off > 0; off >>= 1) ss += __shfl_down(ss, off);
    __shared__ float wsum[4];
    __shared__ float inv_s;
    int lane = t & 63, wid = t >> 6;
    if (lane == 0) wsum[wid] = ss;
    __syncthreads();
    if (t == 0) {
        float tot = wsum[0] + wsum[1] + wsum[2] + wsum[3];
        inv_s = rsqrtf(tot * (1.0f / Dv) + 1e-8f);
    }
    __syncthreads();
    float inv = inv_s;
    float4 sc = *(const float4*)(scale + t * 4);
    bf16x4 ob = {(bf16)(xv[0] * inv * sc.x), (bf16)(xv[1] * inv * sc.y),
                 (bf16)(xv[2] * inv * sc.z), (bf16)(xv[3] * inv * sc.w)};
    *(bf16x4*)(outb + (size_t)row * Dv + t * 4) = ob;
}

// ---------------- unified prep: weight transposes + h_normT + uvT ----------------
__global__ void prep_kernel(const float* __restrict__ proj_w, const float* __restrict__ up_w,
                            const float* __restrict__ down_w,
                            const float* __restrict__ u, const float* __restrict__ v,
                            const bf16* __restrict__ hnb,
                            bf16* __restrict__ proj_wT, bf16* __restrict__ up_wT,
                            bf16* __restrict__ down_wT, bf16* __restrict__ h_normT,
                            bf16* __restrict__ uvT) {
    __shared__ float tile[32][33];
    int blk = blockIdx.x;
    int t = threadIdx.x;
    if (blk >= 7168) {  // uvT
        int i = (blk - 7168) * 256 + t;
        int rcol = i >> 10, d = i & (Wv - 1);
        float val = (rcol < Rv) ? u[(size_t)d * Rv + rcol] : v[(size_t)d * Rv + (rcol - Rv)];
        uvT[i] = (bf16)val;
        return;
    }
    const void* src;
    bf16* dst;
    int rows, cols, r0, c0;
    bool f32src = true;
    if (blk < 1024) {
        src = proj_w; dst = proj_wT; rows = 1024; cols = 1024;
        c0 = (blk & 31) * 32; r0 = (blk >> 5) * 32;
    } else if (blk < 3072) {
        int idx = blk - 1024;
        src = up_w; dst = up_wT; rows = 1024; cols = 2048;
        c0 = (idx & 63) * 32; r0 = (idx >> 6) * 32;
    } else if (blk < 5120) {
        int idx = blk - 3072;
        src = down_w; dst = down_wT; rows = 2048; cols = 1024;
        c0 = (idx & 31) * 32; r0 = (idx >> 5) * 32;
    } else {
        int idx = blk - 5120;
        int b = idx >> 10; idx &= 1023;
        src = hnb + (size_t)b * Wv * Dv; dst = h_normT + (size_t)b * Dv * Wv;
        rows = 1024; cols = 1024; f32src = false;
        c0 = (idx & 31) * 32; r0 = (idx >> 5) * 32;
    }
    int r = t >> 3, c4 = (t & 7) * 4;
    float vv[4];
    if (f32src) {
        float4 x = *(const float4*)((const float*)src + (size_t)(r0 + r) * cols + c0 + c4);
        vv[0] = x.x; vv[1] = x.y; vv[2] = x.z; vv[3] = x.w;
    } else {
        bf16x4 x = *(const bf16x4*)((const bf16*)src + (size_t)(r0 + r) * cols + c0 + c4);
        vv[0] = (float)x[0]; vv[1] = (float)x[1]; vv[2] = (float)x[2]; vv[3] = (float)x[3];
    }
    tile[r][c4 + 0] = vv[0];
    tile[r][c4 + 1] = vv[1];
    tile[r][c4 + 2] = vv[2];
    tile[r][c4 + 3] = vv[3];
    __syncthreads();
    int n = t >> 3, k4 = (t & 7) * 4;
    bf16x4 ob = {(bf16)tile[k4 + 0][n], (bf16)tile[k4 + 1][n],
                 (bf16)tile[k4 + 2][n], (bf16)tile[k4 + 3][n]};
    *(bf16x4*)(dst + (size_t)(c0 + n) * rows + r0 + k4) = ob;
}

// ---------------- qk via MFMA: [Q|K] = l2norm(hnb @ uvT^T) with gamma folding ----------------
__global__ __launch_bounds__(256) void qk_mfma(
    const bf16* __restrict__ hnb,   // [B*W][D]
    const bf16* __restrict__ uvT,   // [32][D]
    const float* __restrict__ decay_logit,
    bf16* __restrict__ Qs, bf16* __restrict__ Ks) {  // [B*W][16]
    int t = threadIdx.x, lane = t & 63, wid = t >> 6;
    int wm = wid >> 1, wn = wid & 1;
    int row0 = blockIdx.x * 32 + wm * 16;
    const bf16* Arow = hnb + (size_t)(row0 + (lane & 15)) * Dv + (lane >> 4) * 8;
    const bf16* Brow = uvT + (size_t)(wn * 16 + (lane & 15)) * Dv + (lane >> 4) * 8;
    f32x4 acc = {};
#pragma unroll 8
    for (int k0 = 0; k0 < Dv; k0 += 32) {
        bf16x8 a = *(const bf16x8*)(Arow + k0);
        bf16x8 b = *(const bf16x8*)(Brow + k0);
        acc = __builtin_amdgcn_mfma_f32_16x16x32_bf16(a, b, acc, 0, 0, 0);
    }
    int col = lane & 15;  // r index
    float dl = decay_logit[col];
    float gamma = 0.85f + 0.15f * sigmoidf_(dl);
    float logg = log2f(gamma);
#pragma unroll
    for (int r = 0; r < 4; ++r) {
        float vv = acc[r];
        float ss = vv * vv;
#pragma unroll
        for (int m = 1; m < 16; m <<= 1) ss += __shfl_xor(ss, m);
        float nrm = fmaxf(sqrtf(ss), 1e-8f);
        float val = vv / nrm;
        int grow = row0 + (lane >> 4) * 4 + r;
        int i = grow & (Wv - 1);
        if (wn == 0) {
            float pw = exp2f((float)i * logg);
            Qs[(size_t)grow * Rv + col] = (bf16)(val * pw);
        } else {
            float pwi = exp2f(-(float)i * logg);
            Ks[(size_t)grow * Rv + col] = (bf16)(val * pwi);
        }
    }
}

// ---------------- S tile build via MFMA: S = gate*kb + alpha*(Q~ @ K~^T), causal ----------------
__global__ __launch_bounds__(256) void sbuild_mfma(
    const bf16* __restrict__ Qs, const bf16* __restrict__ Ks,
    const float* __restrict__ kbase,
    const float* __restrict__ gate_logit,
    const float* __restrict__ alpha_logit,
    bf16* __restrict__ S) {
    int it = blockIdx.y, jt = blockIdx.x;
    if (jt > it) return;
    int b = blockIdx.z;
    int t = threadIdx.x, lane = t & 63, wid = t >> 6;
    int wm = wid >> 1, wn = wid & 1;
    int i0 = it * 64, j0 = jt * 64;
    int l15 = lane & 15, chunk = lane >> 4;
    bf16x8 af[2], bfr[2];
    bf16x8 z8 = {};
#pragma unroll
    for (int mi = 0; mi < 2; ++mi)
        af[mi] = (chunk < 2)
            ? *(const bf16x8*)(Qs + (size_t)(b * Wv + i0 + wm * 32 + mi * 16 + l15) * Rv + chunk * 8)
            : z8;
#pragma unroll
    for (int ni = 0; ni < 2; ++ni)
        bfr[ni] = (chunk < 2)
            ? *(const bf16x8*)(Ks + (size_t)(b * Wv + j0 + wn * 32 + ni * 16 + l15) * Rv + chunk * 8)
            : z8;
    f32x4 acc[2][2] = {};
#pragma unroll
    for (int mi = 0; mi < 2; ++mi)
#pragma unroll
        for (int ni = 0; ni < 2; ++ni)
            acc[mi][ni] = __builtin_amdgcn_mfma_f32_16x16x32_bf16(af[mi], bfr[ni], acc[mi][ni], 0, 0, 0);
    float gate = sigmoidf_(gate_logit[0]);
    float alpha = sigmoidf_(alpha_logit[0]);
#pragma unroll
    for (int mi = 0; mi < 2; ++mi)
#pragma unroll
        for (int ni = 0; ni < 2; ++ni) {
            int j = j0 + wn * 32 + ni * 16 + l15;
#pragma unroll
            for (int r = 0; r < 4; ++r) {
                int i = i0 + wm * 32 + mi * 16 + chunk * 4 + r;
                float s = (j <= i) ? gate * kbase[(size_t)i * Wv + j] + alpha * acc[mi][ni][r] : 0.f;
                S[((size_t)b * Wv + i) * Wv + j] = (bf16)s;
            }
        }
}

// ---------------- MFMA GEMM, depth-3 pipelined ----------------
// C = [gelu](A @ Bt^T + bias) [+ res], A:[M][K] Bt:[N][K] bf16.
// BM=BN=BK=64, 256 threads = 4 waves in 2x2; wave computes 32x32.
// 3 LDS stage buffers; counted s_waitcnt vmcnt(8) keeps 2 tiles in flight.
// XOR-swizzled LDS (16B granule, XOR row&7) via pre-swizzled global source.
// RES: 0 none, 1 f32, 2 bf16.
template <bool GELU, bool OUT_BF16, int RES, bool CAUSAL>
__global__ __launch_bounds__(256) void mfma_gemm(
    const bf16* __restrict__ A, const bf16* __restrict__ Bt,
    const float* __restrict__ bias, const void* __restrict__ res,
    void* __restrict__ Cout, int M, int N, int K,
    long sA, long sB, long sC) {
    constexpr int BM = 64, BN = 64, BK = 64;
    __shared__ bf16 As[3][BM * BK];
    __shared__ bf16 Bs[3][BN * BK];
    int bz = blockIdx.z;
    A += (size_t)bz * sA;
    Bt += (size_t)bz * sB;
    const int m0 = blockIdx.y * BM, n0 = blockIdx.x * BN;
    const int t = threadIdx.x;
    const int lane = t & 63, wid = t >> 6;
    const int wm = wid >> 1, wn = wid & 1;
    f32x4 acc[2][2] = {};

    const int Klim = CAUSAL ? (m0 + BM < K ? m0 + BM : K) : K;
    const int nt = Klim >> 6;  // Klim is always a multiple of 64 here

    // staging source (per-lane, swizzled granule): row fr0 (+32 for second half),
    // physical granule (t&7) receives logical granule fcs = (t&7)^(fr0&7).
    const int fr0 = t >> 3;
    const int fcs = (t & 7) ^ (fr0 & 7);
    const bf16* Asrc = A + (size_t)(m0 + fr0) * K + fcs * 8;
    const bf16* Bsrc = Bt + (size_t)(n0 + fr0) * K + fcs * 8;

    const int q = lane >> 4, s = lane & 7, l15 = lane & 15;

#define STAGE(sb, kt)                                                        \
    do {                                                                     \
        const bf16* a_ = Asrc + (size_t)(kt) * BK;                           \
        const bf16* b_ = Bsrc + (size_t)(kt) * BK;                           \
        gload_lds16(a_, &As[sb][wid * 512]);                                 \
        gload_lds16(a_ + (size_t)32 * K, &As[sb][2048 + wid * 512]);         \
        gload_lds16(b_, &Bs[sb][wid * 512]);                                 \
        gload_lds16(b_ + (size_t)32 * K, &Bs[sb][2048 + wid * 512]);         \
    } while (0)

    // prologue: fill 3 stages (clamped; duplicates are harmless)
    STAGE(0, 0);
    STAGE(1, nt > 1 ? 1 : nt - 1);
    STAGE(2, nt > 2 ? 2 : nt - 1);

    int cur = 0;
    for (int tt = 0; tt < nt; ++tt) {
        // wait only for the oldest stage's 4 loads; 8 newer stay in flight
        asm volatile("s_waitcnt vmcnt(8)" ::: "memory");
        __builtin_amdgcn_s_barrier();

        bf16x8 af[2][2], bfr[2][2];
#pragma unroll
        for (int mi = 0; mi < 2; ++mi)
#pragma unroll
            for (int kk = 0; kk < 2; ++kk) {
                af[mi][kk] = *(const bf16x8*)&As[cur][(wm * 32 + mi * 16 + l15) * BK + (((kk * 4 + q) ^ s) * 8)];
                bfr[mi][kk] = *(const bf16x8*)&Bs[cur][(wn * 32 + mi * 16 + l15) * BK + (((kk * 4 + q) ^ s) * 8)];
            }
#pragma unroll
        for (int kk = 0; kk < 2; ++kk)
#pragma unroll
            for (int mi = 0; mi < 2; ++mi)
#pragma unroll
                for (int ni = 0; ni < 2; ++ni)
                    acc[mi][ni] = __builtin_amdgcn_mfma_f32_16x16x32_bf16(
                        af[mi][kk], bfr[ni][kk], acc[mi][ni], 0, 0, 0);

        __builtin_amdgcn_s_barrier();  // all waves done reading stage 'cur'
        int kn = (tt + 3 < nt) ? tt + 3 : nt - 1;
        STAGE(cur, kn);  // restage consumed buffer (dup at tail, harmless)
        cur = (cur == 2) ? 0 : cur + 1;
    }
#undef STAGE

    const int row_base = m0 + wm * 32;
    const int col_base = n0 + wn * 32;
#pragma unroll
    for (int mi = 0; mi < 2; ++mi) {
#pragma unroll
        for (int ni = 0; ni < 2; ++ni) {
            int col = col_base + ni * 16 + l15;
            float bv = bias ? bias[col] : 0.f;
#pragma unroll
            for (int r = 0; r < 4; ++r) {
                int row = row_base + mi * 16 + q * 4 + r;
                float val = acc[mi][ni][r] + bv;
                if (GELU) val = 0.5f * val * (1.0f + erff(val * 0.7071067811865476f));
                if (RES == 1)
                    val += ((const float*)res)[(size_t)bz * sC + (size_t)row * N + col];
                else if (RES == 2)
                    val += (float)((const bf16*)res)[(size_t)bz * sC + (size_t)row * N + col];
                if (OUT_BF16)
                    ((bf16*)Cout)[(size_t)bz * sC + (size_t)row * N + col] = (bf16)val;
                else
                    ((float*)Cout)[(size_t)bz * sC + (size_t)row * N + col] = val;
            }
        }
    }
}

extern "C" void kernel_launch(void* const* d_in, const int* in_sizes, int n_in,
                              void* d_out, int out_size, void* d_ws, size_t ws_size,
                              hipStream_t stream) {
    const float* h = (const float*)d_in[0];
    const float* decay_logit = (const float*)d_in[1];
    const float* k_base = (const float*)d_in[2];
    const float* gate_logit = (const float*)d_in[3];
    const float* u = (const float*)d_in[4];
    const float* v = (const float*)d_in[5];
    const float* alpha_logit = (const float*)d_in[6];
    const float* proj_w = (const float*)d_in[7];
    const float* proj_b = (const float*)d_in[8];
    const float* n1 = (const float*)d_in[9];
    const float* n2 = (const float*)d_in[10];
    const float* up_w = (const float*)d_in[11];
    const float* up_b = (const float*)d_in[12];
    const float* down_w = (const float*)d_in[13];
    const float* down_b = (const float*)d_in[14];
    float* out = (float*)d_out;

    char* ws = (char*)d_ws;
    bf16* hnb = (bf16*)ws;        ws += (size_t)Bv * Wv * Dv * 2;       // 4 MB
    bf16* h_normT = (bf16*)ws;    ws += (size_t)Bv * Dv * Wv * 2;       // 4 MB
    bf16* uvT = (bf16*)ws;        ws += (size_t)32 * Wv * 2;            // 64 KB
    bf16* Qs = (bf16*)ws;         ws += (size_t)Bv * Wv * Rv * 2;       // 64 KB
    bf16* Ks = (bf16*)ws;         ws += (size_t)Bv * Wv * Rv * 2;       // 64 KB
    bf16* S = (bf16*)ws;          ws += (size_t)Bv * Wv * Wv * 2;       // 4 MB
    bf16* out_s = (bf16*)ws;      ws += (size_t)Bv * Wv * Dv * 2;       // 4 MB
    bf16* h2b = (bf16*)ws;        ws += (size_t)Bv * Wv * Dv * 2;       // 4 MB
    bf16* h2n = (bf16*)ws;        ws += (size_t)Bv * Wv * Dv * 2;       // 4 MB
    bf16* g = (bf16*)ws;          ws += (size_t)Bv * Wv * 2 * Dv * 2;   // 8 MB
    bf16* proj_wT = (bf16*)ws;    ws += (size_t)Dv * Dv * 2;            // 2 MB
    bf16* up_wT = (bf16*)ws;      ws += (size_t)2 * Dv * Dv * 2;        // 4 MB
    bf16* down_wT = (bf16*)ws;    ws += (size_t)2 * Dv * Dv * 2;        // 4 MB

    int rows = Bv * Wv;  // 2048

    // 1. hnb = rmsnorm(h, norm1_scale) bf16
    rmsnorm_kernel<false><<<rows, 256, 0, stream>>>(h, n1, hnb);
    // 2. all transposes + uvT in one launch
    prep_kernel<<<7296, 256, 0, stream>>>(proj_w, up_w, down_w, u, v, hnb,
                                          proj_wT, up_wT, down_wT, h_normT, uvT);
    // 3. q,k via MFMA with gamma folding
    qk_mfma<<<rows / 32, 256, 0, stream>>>(hnb, uvT, decay_logit, Qs, Ks);
    // 4. S = gate*kb + alpha*(Q~ @ K~^T), causal tiles
    sbuild_mfma<<<dim3(Wv / 64, Wv / 64, Bv), 256, 0, stream>>>(
        Qs, Ks, k_base, gate_logit, alpha_logit, S);
    // 5. out_s = S @ h_norm  (batched, causal-K, bf16 out)
    mfma_gemm<false, true, 0, true><<<dim3(Dv / 64, Wv / 64, Bv), 256, 0, stream>>>(
        S, h_normT, nullptr, nullptr, out_s, Wv, Dv, Wv,
        (long)Wv * Wv, (long)Dv * Wv, (long)Wv * Dv);
    // 6. h2b = h + out_s @ proj_w + proj_b  (bf16 out, f32 res)
    mfma_gemm<false, true, 1, false><<<dim3(Dv / 64, rows / 64, 1), 256, 0, stream>>>(
        out_s, proj_wT, proj_b, h, h2b, rows, Dv, Dv, 0, 0, 0);
    // 7. h2n = rmsnorm(h2b, norm2_scale)  (bf16 in/out)
    rmsnorm_kernel<true><<<rows, 256, 0, stream>>>(h2b, n2, h2n);
    // 8. g = gelu(h2n @ up_w + up_b)  (bf16 out)
    mfma_gemm<true, true, 0, false><<<dim3(2 * Dv / 64, rows / 64, 1), 256, 0, stream>>>(
        h2n, up_wT, up_b, nullptr, g, rows, 2 * Dv, Dv, 0, 0, 0);
    // 9. out = h2b + g @ down_w + down_b  (f32 out, bf16 res)
    mfma_gemm<false, false, 2, false><<<dim3(Dv / 64, rows / 64, 1), 256, 0, stream>>>(
        g, down_wT, down_b, h2b, out, rows, Dv, 2 * Dv, 0, 0, 0);
}